// Round 5
// baseline (434.854 us; speedup 1.0000x reference)
//
#include <hip/hip_runtime.h>

#define BN 4096
#define BD 128
#define NB 4
#define TOPK 20
#define CAND 128
#define EPS 0.06f

typedef float f32x4 __attribute__((ext_vector_type(4)));
typedef short bf16x8 __attribute__((ext_vector_type(8)));

__device__ inline unsigned short f2bf(float f) {
  unsigned int u = __float_as_uint(f);
  unsigned int r = (u + 0x7FFFu + ((u >> 16) & 1u)) >> 16;
  return (unsigned short)r;
}

// ---------------- Projection (f64 accumulate) -> Qd, Kd (f64) + Khi (bf16) ----------------
__global__ __launch_bounds__(256) void proj_kernel(
    const float* __restrict__ x,
    const float* __restrict__ Wq, const float* __restrict__ bq,
    const float* __restrict__ Wk, const float* __restrict__ bk,
    double* __restrict__ Qd, double* __restrict__ Kd, unsigned short* __restrict__ Khi) {
  __shared__ double xs[32][129];
  const int tid = threadIdx.x;
  const long row0 = (long)blockIdx.x * 32;
  const float* xsrc = x + row0 * BD;
  for (int i = tid; i < 32 * BD; i += 256) xs[i >> 7][i & 127] = (double)xsrc[i];
  __syncthreads();

  const int e = tid & 127;
  const bool isK = tid >= 128;
  const float* W = isK ? Wk : Wq;
  const float* bias = isK ? bk : bq;
  double* Od = isK ? Kd : Qd;

  double acc[32];
  const double binit = (double)bias[e];
#pragma unroll
  for (int r = 0; r < 32; ++r) acc[r] = binit;

  for (int d = 0; d < BD; ++d) {
    const double wv = (double)W[d * BD + e];
#pragma unroll
    for (int r = 0; r < 32; ++r) acc[r] = fma(xs[r][d], wv, acc[r]);
  }

#pragma unroll
  for (int r = 0; r < 32; ++r) {
    const double a = acc[r];
    const long o = (row0 + r) * BD + e;
    Od[o] = a;
    if (isK) Khi[o] = f2bf((float)a);
  }
}

// ---------------- Screen: bf16 MFMA + pooled-exact tau + candidate emit ----------------
// Block = 8 waves (512 thr), 16 q-rows; wave w covers t-eighth [w*32, w*32+32) (32 tiles).
// Single 16-row tile per wave: C col(lane&15)=q-row, C row((lane>>4)*4+reg)=kv-in-tile.
// tau per row = 20th largest of pooled per-lane top-2 (8 waves x 4 lanes x 2 = 64 values).
__global__ __launch_bounds__(512) void screen_kernel(
    const double* __restrict__ Qd, const unsigned short* __restrict__ Khi,
    unsigned short* __restrict__ cand, unsigned int* __restrict__ cnt) {
  const int tid = threadIdx.x;
  const int lane = tid & 63;
  const int w = tid >> 6;                        // t-eighth
  const int blk = blockIdx.x;
  const int b = (blk & 7) >> 1;                  // XCD-affinity: 2 XCDs per batch
  const int i = ((blk >> 3) << 1) | (blk & 1);   // 0..255
  const int rowbase = i << 4;                    // 16 rows per block
  const int lq = lane & 15;
  const int gg = lane >> 4;
  const float RS = 0.088388347648318447f;

  __shared__ float pool[16][64];
  __shared__ float tauLds[16];
  __shared__ unsigned int scnt[16];
  __shared__ unsigned short slist[16][CAND];

  if (tid < 16) scnt[tid] = 0;

  // Q fragment, single row-tile x 4 k-steps (from f64 Qd, one-time)
  bf16x8 bqf[4];
  {
    const double* qp = Qd + ((long)b * BN + rowbase + lq) * BD;
#pragma unroll
    for (int ks = 0; ks < 4; ++ks) {
      const int dbase = ks * 32 + gg * 8;
      bf16x8 pk;
#pragma unroll
      for (int j = 0; j < 8; ++j) pk[j] = (short)f2bf((float)qp[dbase + j]);
      bqf[ks] = pk;
    }
  }

  const unsigned short* kb = Khi + (long)b * BN * BD;
  const long arow = (long)lq * BD + gg * 8;      // A-frag offset within tile
  const int t0 = w * 32;

  // ---- pass 1: per-lane top-2 (rotating in-place A loads) ----
  float t1 = -3.4e38f, t2 = -3.4e38f;
  bf16x8 a[4];
#pragma unroll
  for (int ks = 0; ks < 4; ++ks)
    a[ks] = *(const bf16x8*)(kb + (long)t0 * 16 * BD + arow + ks * 32);
  for (int tt = 0; tt < 32; ++tt) {
    const unsigned short* nb = kb + (long)(t0 + tt + 1) * 16 * BD + arow;
    f32x4 acc = {0.f, 0.f, 0.f, 0.f};
#pragma unroll
    for (int ks = 0; ks < 4; ++ks) {
      acc = __builtin_amdgcn_mfma_f32_16x16x32_bf16(a[ks], bqf[ks], acc, 0, 0, 0);
      a[ks] = *(const bf16x8*)(nb + ks * 32);  // rotate-in next tile (tail read stays in ws)
    }
#pragma unroll
    for (int reg = 0; reg < 4; ++reg) {
      const float s = acc[reg] * RS;
      const float m1 = fmaxf(t1, s);
      t2 = fmaxf(t2, fminf(t1, s));
      t1 = m1;
    }
  }

  pool[lq][w * 8 + gg * 2 + 0] = t1;
  pool[lq][w * 8 + gg * 2 + 1] = t2;
  __syncthreads();

  // ---- tau: bitonic-64 ascending per row; 20th largest at index 44 ----
  for (int rr = 0; rr < 2; ++rr) {
    const int r = w * 2 + rr;
    float v = pool[r][lane];
#pragma unroll
    for (int k = 2; k <= 64; k <<= 1) {
#pragma unroll
      for (int j = k >> 1; j > 0; j >>= 1) {
        const float o = __shfl_xor(v, j);
        const bool keepmin = (((lane & k) == 0) == ((lane & j) == 0));
        v = keepmin ? fminf(v, o) : fmaxf(v, o);
      }
    }
    const float tau = __shfl(v, 44);
    if (lane == 0) tauLds[r] = tau;
  }
  __syncthreads();

  const float th = tauLds[lq] - EPS;

  // ---- pass 2: identical MFMAs, emit candidates ----
#pragma unroll
  for (int ks = 0; ks < 4; ++ks)
    a[ks] = *(const bf16x8*)(kb + (long)t0 * 16 * BD + arow + ks * 32);
  for (int tt = 0; tt < 32; ++tt) {
    const unsigned short* nb = kb + (long)(t0 + tt + 1) * 16 * BD + arow;
    f32x4 acc = {0.f, 0.f, 0.f, 0.f};
#pragma unroll
    for (int ks = 0; ks < 4; ++ks) {
      acc = __builtin_amdgcn_mfma_f32_16x16x32_bf16(a[ks], bqf[ks], acc, 0, 0, 0);
      a[ks] = *(const bf16x8*)(nb + ks * 32);
    }
#pragma unroll
    for (int reg = 0; reg < 4; ++reg) {
      const float s = acc[reg] * RS;
      if (s >= th) {
        unsigned int p = atomicAdd(&scnt[lq], 1u);
        if (p < CAND) slist[lq][p] = (unsigned short)((t0 + tt) * 16 + gg * 4 + reg);
      }
    }
  }
  __syncthreads();

  const long growbase = (long)b * BN + rowbase;
  if (tid < 16) cnt[growbase + tid] = min(scnt[tid], (unsigned int)CAND);
  const unsigned short* sl = &slist[0][0];
  for (int j = tid; j < 16 * CAND; j += 512) cand[growbase * CAND + j] = sl[j];
}

// ---------------- Finalize: wave-per-row, barrier-free ----------------
__device__ inline float rescore_f64(const double2* __restrict__ kp2, const double2* __restrict__ q2) {
  double a0 = 0.0, a1 = 0.0, a2 = 0.0, a3 = 0.0;
#pragma unroll
  for (int i = 0; i < 64; i += 4) {
    a0 = fma(q2[i + 0].y, kp2[i + 0].y, fma(q2[i + 0].x, kp2[i + 0].x, a0));
    a1 = fma(q2[i + 1].y, kp2[i + 1].y, fma(q2[i + 1].x, kp2[i + 1].x, a1));
    a2 = fma(q2[i + 2].y, kp2[i + 2].y, fma(q2[i + 2].x, kp2[i + 2].x, a2));
    a3 = fma(q2[i + 3].y, kp2[i + 3].y, fma(q2[i + 3].x, kp2[i + 3].x, a3));
  }
  return (float)(((a0 + a1) + (a2 + a3)) * 8.8388347648318447e-02);
}

__device__ inline unsigned int fmono(float v) {
  const unsigned int u = __float_as_uint(v);
  return (u & 0x80000000u) ? ~u : (u | 0x80000000u);
}
__device__ inline float fdemono(unsigned int k) {
  const unsigned int u = (k & 0x80000000u) ? (k & 0x7fffffffu) : ~k;
  return __uint_as_float(u);
}

__global__ __launch_bounds__(256) void finalize_kernel(
    const double* __restrict__ Qd, const double* __restrict__ Kd,
    const unsigned short* __restrict__ cand, const unsigned int* __restrict__ cnt,
    float* __restrict__ out) {
  const int tid = threadIdx.x;
  const int lane = tid & 63;
  const int w = tid >> 6;
  const long row = (long)blockIdx.x * 4 + w;   // global q-row 0..16383
  const int b = (int)(row >> 12);
  float* outrow = out + row * BN;
  const double* kb = Kd + (long)b * BN * BD;
  const double2* q2 = (const double2*)(Qd + row * BD);

  const int c = (int)min(cnt[row], (unsigned int)CAND);

  // up to 2 candidates per lane, packed sortable key: (mono(val) << 12) | (4095 - col)
  unsigned long long key0 = 0ull, key1 = 0ull;
  if (lane < c) {
    const int kv = (int)cand[row * CAND + lane];
    const float v = rescore_f64((const double2*)(kb + (long)kv * BD), q2);
    key0 = ((unsigned long long)fmono(v) << 12) | (unsigned int)(4095 - kv);
  }
  if (lane + 64 < c) {
    const int kv = (int)cand[row * CAND + lane + 64];
    const float v = rescore_f64((const double2*)(kb + (long)kv * BD), q2);
    key1 = ((unsigned long long)fmono(v) << 12) | (unsigned int)(4095 - kv);
  }
  if (key1 > key0) { const unsigned long long t = key0; key0 = key1; key1 = t; }

  float m = 0.0f, se = 0.0f;
  float myval = 0.0f;
  int mycol = 0;
  for (int it = 0; it < TOPK; ++it) {
    unsigned long long rk = key0;
    for (int off = 32; off; off >>= 1) {
      const unsigned long long ok = __shfl_xor(rk, off);
      rk = (ok > rk) ? ok : rk;
    }
    const float rv = fdemono((unsigned int)(rk >> 12));
    if (it == 0) m = fmaxf(rv, 0.0f);
    se += expf(rv - m);
    if (lane == it) { myval = rv; mycol = 4095 - (int)(rk & 0xFFFull); }
    if (key0 == rk) { key0 = key1; key1 = 0ull; }
  }

  const float Z = se + (float)(BN - TOPK) * expf(-m);
  const float c0 = expf(-m) / Z;

  // const fill of own row (coalesced float4), then fence, then scatter specials
  const float4 cv = make_float4(c0, c0, c0, c0);
  float4* op = (float4*)outrow;
#pragma unroll
  for (int i = 0; i < 16; ++i) op[i * 64 + lane] = cv;

  asm volatile("s_waitcnt vmcnt(0)" ::: "memory");
  if (lane < TOPK) outrow[mycol] = expf(myval - m) / Z;
}

extern "C" void kernel_launch(void* const* d_in, const int* in_sizes, int n_in,
                              void* d_out, int out_size, void* d_ws, size_t ws_size,
                              hipStream_t stream) {
  const float* x  = (const float*)d_in[0];
  const float* Wq = (const float*)d_in[1];
  const float* bq = (const float*)d_in[2];
  const float* Wk = (const float*)d_in[3];
  const float* bk = (const float*)d_in[4];
  float* out = (float*)d_out;

  const long NE = (long)NB * BN * BD;  // 2,097,152 elements
  double* Qd = (double*)d_ws;                          // 16 MB
  double* Kd = Qd + NE;                                // 16 MB
  unsigned short* Khi = (unsigned short*)(Kd + NE);    // 4 MB
  unsigned short* cand = Khi + NE;                     // 4 MB (NB*BN*CAND)
  unsigned int* cnt = (unsigned int*)(cand + (long)NB * BN * CAND);  // 64 KB

  proj_kernel<<<NB * BN / 32, 256, 0, stream>>>(x, Wq, bq, Wk, bk, Qd, Kd, Khi);
  screen_kernel<<<NB * (BN / 16), 512, 0, stream>>>(Qd, Khi, cand, cnt);
  finalize_kernel<<<NB * BN / 4, 256, 0, stream>>>(Qd, Kd, cand, cnt, out);
}

// Round 6
// 389.242 us; speedup vs baseline: 1.1172x; 1.1172x over previous
//
#include <hip/hip_runtime.h>

#define BN 4096
#define BD 128
#define NB 4
#define TOPK 20
#define CAND 128
#define EPS 0.06f

typedef float f32x16 __attribute__((ext_vector_type(16)));
typedef short bf16x8 __attribute__((ext_vector_type(8)));

__device__ inline unsigned short f2bf(float f) {
  unsigned int u = __float_as_uint(f);
  unsigned int r = (u + 0x7FFFu + ((u >> 16) & 1u)) >> 16;
  return (unsigned short)r;
}

// ---------------- Projection (f64 accumulate) -> Qd, Kd (f64) + Khi (bf16) ----------------
__global__ __launch_bounds__(256) void proj_kernel(
    const float* __restrict__ x,
    const float* __restrict__ Wq, const float* __restrict__ bq,
    const float* __restrict__ Wk, const float* __restrict__ bk,
    double* __restrict__ Qd, double* __restrict__ Kd, unsigned short* __restrict__ Khi) {
  __shared__ double xs[32][129];
  const int tid = threadIdx.x;
  const long row0 = (long)blockIdx.x * 32;
  const float* xsrc = x + row0 * BD;
  for (int i = tid; i < 32 * BD; i += 256) xs[i >> 7][i & 127] = (double)xsrc[i];
  __syncthreads();

  const int e = tid & 127;
  const bool isK = tid >= 128;
  const float* W = isK ? Wk : Wq;
  const float* bias = isK ? bk : bq;
  double* Od = isK ? Kd : Qd;

  double acc[32];
  const double binit = (double)bias[e];
#pragma unroll
  for (int r = 0; r < 32; ++r) acc[r] = binit;

  for (int d = 0; d < BD; ++d) {
    const double wv = (double)W[d * BD + e];
#pragma unroll
    for (int r = 0; r < 32; ++r) acc[r] = fma(xs[r][d], wv, acc[r]);
  }

#pragma unroll
  for (int r = 0; r < 32; ++r) {
    const double a = acc[r];
    const long o = (row0 + r) * BD + e;
    Od[o] = a;
    if (isK) Khi[o] = f2bf((float)a);
  }
}

// ---------------- Screen: LDS-staged 32x32x16 MFMA, pooled tau, candidate emit ----------------
// Block = 8 waves (512 thr), 64 q-rows (2 q-tiles of 32), one batch.
// kv in steps of 128 (4 kv-tiles of 32) staged in 32KB LDS (XOR-swizzled 16B chunks).
// Wave w: kv-tile kt=w&3, q-tile qt=w>>2. MFMA D=K_tile*Q_tile:
//   C col(lane&31)=q, C row((reg&3)+8*(reg>>2)+4*(lane>>5))=kv-in-tile.
// tau per row = 20th largest of pooled per-lane top-3 (8 contributors x3 = 24 >= 20).
__global__ __launch_bounds__(512) void screen_kernel(
    const double* __restrict__ Qd, const unsigned short* __restrict__ Khi,
    unsigned short* __restrict__ cand, unsigned int* __restrict__ cnt) {
  __shared__ char kbuf[32768];               // 128 kv x 256B rows, swizzled
  __shared__ unsigned short pool[64][24];    // bf16 (truncated) per-lane top-3
  __shared__ float tauLds[64];
  __shared__ unsigned int scnt[64];
  __shared__ unsigned short slist[64][CAND];

  const int tid = threadIdx.x;
  const int lane = tid & 63;
  const int w = tid >> 6;
  const int kt = w & 3, qt = w >> 2;
  const int c31 = lane & 31, hi = lane >> 5;
  const int blk = blockIdx.x;
  const int b = (blk & 7) >> 1;                    // XCD-affinity: 2 XCDs per batch
  const int ib = ((blk >> 3) << 1) | (blk & 1);    // 0..63
  const int rowbase = ib << 6;                     // 64 rows per block
  const int qrow = qt * 32 + c31;                  // this lane's q-row (fixed)
  const float RS = 0.088388347648318447f;

  // Q B-fragments: 8 k-steps of 16 (lane holds k = ks*16 + hi*8 + j, col = c31)
  bf16x8 bqf[8];
  {
    const double* qp = Qd + ((long)b * BN + rowbase + qrow) * BD + hi * 8;
#pragma unroll
    for (int ks = 0; ks < 8; ++ks) {
      bf16x8 pk;
#pragma unroll
      for (int j = 0; j < 8; ++j) pk[j] = (short)f2bf((float)qp[ks * 16 + j]);
      bqf[ks] = pk;
    }
  }

  const char* kb = (const char*)(Khi + (long)b * BN * BD);  // 1MB per batch
  const int ar = kt * 32 + c31;                             // A row within staged tile
  const int ar256 = ar * 256;
  const int ar7 = ar & 7;

  uint4 stg[4];
#define LOADSTG(s)                                              \
  do {                                                          \
    const char* gsrc_ = kb + (long)(s)*32768 + tid * 16;        \
    stg[0] = *(const uint4*)(gsrc_);                            \
    stg[1] = *(const uint4*)(gsrc_ + 8192);                     \
    stg[2] = *(const uint4*)(gsrc_ + 16384);                    \
    stg[3] = *(const uint4*)(gsrc_ + 24576);                    \
  } while (0)
#define WRITESTG()                                              \
  do {                                                          \
    _Pragma("unroll") for (int j_ = 0; j_ < 4; ++j_) {          \
      const int L_ = j_ * 8192 + tid * 16;                      \
      const int r_ = L_ >> 8;                                   \
      const int c_ = (L_ >> 4) & 15;                            \
      *(uint4*)(kbuf + r_ * 256 + ((c_ ^ (r_ & 7)) << 4)) = stg[j_]; \
    }                                                           \
  } while (0)

  // ---- PASS 1: per-lane top-3 ----
  LOADSTG(0);
  WRITESTG();
  __syncthreads();

  float t1 = -3.4e38f, t2 = -3.4e38f, t3 = -3.4e38f;
  for (int step = 0; step < 32; ++step) {
    if (step < 31) LOADSTG(step + 1);
    f32x16 acc = {0.f, 0.f, 0.f, 0.f, 0.f, 0.f, 0.f, 0.f,
                  0.f, 0.f, 0.f, 0.f, 0.f, 0.f, 0.f, 0.f};
#pragma unroll
    for (int ks = 0; ks < 8; ++ks) {
      const bf16x8 a = *(const bf16x8*)(kbuf + ar256 + (((ks * 2 + hi) ^ ar7) << 4));
      acc = __builtin_amdgcn_mfma_f32_32x32x16_bf16(a, bqf[ks], acc, 0, 0, 0);
    }
#pragma unroll
    for (int reg = 0; reg < 16; ++reg) {
      const float s = acc[reg] * RS;
      const float w1 = fmaxf(t1, s), l1 = fminf(t1, s);
      const float w2 = fmaxf(t2, l1), l2 = fminf(t2, l1);
      t3 = fmaxf(t3, l2);
      t2 = w2;
      t1 = w1;
    }
    __syncthreads();
    if (step < 31) WRITESTG();
    __syncthreads();
  }

  // pool per-lane top-3 (truncate to bf16: always <= original -> tau stays a lower bound)
  {
    const int cid = kt * 2 + hi;
    pool[qrow][cid * 3 + 0] = (unsigned short)(__float_as_uint(t1) >> 16);
    pool[qrow][cid * 3 + 1] = (unsigned short)(__float_as_uint(t2) >> 16);
    pool[qrow][cid * 3 + 2] = (unsigned short)(__float_as_uint(t3) >> 16);
  }
  if (tid < 64) scnt[tid] = 0;
  __syncthreads();

  // ---- tau: bitonic-32 ascending per row (24 values + 8 pads); 20th largest at idx 12 ----
  for (int it2 = 0; it2 < 4; ++it2) {
    const int row = w * 8 + it2 * 2 + hi;
    float v = (c31 < 24) ? __uint_as_float((unsigned int)pool[row][c31] << 16) : -3.4e38f;
#pragma unroll
    for (int k = 2; k <= 32; k <<= 1) {
#pragma unroll
      for (int j = k >> 1; j > 0; j >>= 1) {
        const float o = __shfl_xor(v, j);
        const bool keepmin = (((c31 & k) == 0) == ((c31 & j) == 0));
        v = keepmin ? fminf(v, o) : fmaxf(v, o);
      }
    }
    if (c31 == 12) tauLds[row] = v;
  }
  __syncthreads();

  const float th = tauLds[qrow] - EPS;

  // ---- PASS 2: identical MFMAs, emit candidates ----
  LOADSTG(0);
  WRITESTG();
  __syncthreads();

  for (int step = 0; step < 32; ++step) {
    if (step < 31) LOADSTG(step + 1);
    f32x16 acc = {0.f, 0.f, 0.f, 0.f, 0.f, 0.f, 0.f, 0.f,
                  0.f, 0.f, 0.f, 0.f, 0.f, 0.f, 0.f, 0.f};
#pragma unroll
    for (int ks = 0; ks < 8; ++ks) {
      const bf16x8 a = *(const bf16x8*)(kbuf + ar256 + (((ks * 2 + hi) ^ ar7) << 4));
      acc = __builtin_amdgcn_mfma_f32_32x32x16_bf16(a, bqf[ks], acc, 0, 0, 0);
    }
#pragma unroll
    for (int reg = 0; reg < 16; ++reg) {
      const float s = acc[reg] * RS;
      if (s >= th) {
        const int kv = step * 128 + kt * 32 + ((reg & 3) + 8 * (reg >> 2) + 4 * hi);
        unsigned int p = atomicAdd(&scnt[qrow], 1u);
        if (p < CAND) slist[qrow][p] = (unsigned short)kv;
      }
    }
    __syncthreads();
    if (step < 31) WRITESTG();
    __syncthreads();
  }

  const long growbase = (long)b * BN + rowbase;
  if (tid < 64) cnt[growbase + tid] = min(scnt[tid], (unsigned int)CAND);
  const unsigned short* sl = &slist[0][0];
  for (int j = tid; j < 64 * CAND; j += 512) cand[growbase * CAND + j] = sl[j];
#undef LOADSTG
#undef WRITESTG
}

// ---------------- Finalize: wave-per-row, barrier-free (R5 + XCD batch affinity) ----------------
__device__ inline float rescore_f64(const double2* __restrict__ kp2, const double2* __restrict__ q2) {
  double a0 = 0.0, a1 = 0.0, a2 = 0.0, a3 = 0.0;
#pragma unroll
  for (int i = 0; i < 64; i += 4) {
    a0 = fma(q2[i + 0].y, kp2[i + 0].y, fma(q2[i + 0].x, kp2[i + 0].x, a0));
    a1 = fma(q2[i + 1].y, kp2[i + 1].y, fma(q2[i + 1].x, kp2[i + 1].x, a1));
    a2 = fma(q2[i + 2].y, kp2[i + 2].y, fma(q2[i + 2].x, kp2[i + 2].x, a2));
    a3 = fma(q2[i + 3].y, kp2[i + 3].y, fma(q2[i + 3].x, kp2[i + 3].x, a3));
  }
  return (float)(((a0 + a1) + (a2 + a3)) * 8.8388347648318447e-02);
}

__device__ inline unsigned int fmono(float v) {
  const unsigned int u = __float_as_uint(v);
  return (u & 0x80000000u) ? ~u : (u | 0x80000000u);
}
__device__ inline float fdemono(unsigned int k) {
  const unsigned int u = (k & 0x80000000u) ? (k & 0x7fffffffu) : ~k;
  return __uint_as_float(u);
}

__global__ __launch_bounds__(256) void finalize_kernel(
    const double* __restrict__ Qd, const double* __restrict__ Kd,
    const unsigned short* __restrict__ cand, const unsigned int* __restrict__ cnt,
    float* __restrict__ out) {
  const int tid = threadIdx.x;
  const int lane = tid & 63;
  const int w = tid >> 6;
  const int blk = blockIdx.x;
  const int b = (blk & 7) >> 1;                    // XCD-affinity: 2 XCDs per batch
  const int idx = ((blk >> 3) << 1) | (blk & 1);   // 0..1023
  const long row = (long)b * BN + idx * 4 + w;     // global q-row
  float* outrow = out + row * BN;
  const double* kb = Kd + (long)b * BN * BD;
  const double2* q2 = (const double2*)(Qd + row * BD);

  const int c = (int)min(cnt[row], (unsigned int)CAND);

  // up to 2 candidates per lane, packed sortable key: (mono(val) << 12) | (4095 - col)
  unsigned long long key0 = 0ull, key1 = 0ull;
  if (lane < c) {
    const int kv = (int)cand[row * CAND + lane];
    const float v = rescore_f64((const double2*)(kb + (long)kv * BD), q2);
    key0 = ((unsigned long long)fmono(v) << 12) | (unsigned int)(4095 - kv);
  }
  if (lane + 64 < c) {
    const int kv = (int)cand[row * CAND + lane + 64];
    const float v = rescore_f64((const double2*)(kb + (long)kv * BD), q2);
    key1 = ((unsigned long long)fmono(v) << 12) | (unsigned int)(4095 - kv);
  }
  if (key1 > key0) { const unsigned long long t = key0; key0 = key1; key1 = t; }

  float m = 0.0f, se = 0.0f;
  float myval = 0.0f;
  int mycol = 0;
  for (int it = 0; it < TOPK; ++it) {
    unsigned long long rk = key0;
    for (int off = 32; off; off >>= 1) {
      const unsigned long long ok = __shfl_xor(rk, off);
      rk = (ok > rk) ? ok : rk;
    }
    const float rv = fdemono((unsigned int)(rk >> 12));
    if (it == 0) m = fmaxf(rv, 0.0f);
    se += expf(rv - m);
    if (lane == it) { myval = rv; mycol = 4095 - (int)(rk & 0xFFFull); }
    if (key0 == rk) { key0 = key1; key1 = 0ull; }
  }

  const float Z = se + (float)(BN - TOPK) * expf(-m);
  const float c0 = expf(-m) / Z;

  // const fill of own row (coalesced float4), then fence, then scatter specials
  const float4 cv = make_float4(c0, c0, c0, c0);
  float4* op = (float4*)outrow;
#pragma unroll
  for (int i = 0; i < 16; ++i) op[i * 64 + lane] = cv;

  asm volatile("s_waitcnt vmcnt(0)" ::: "memory");
  if (lane < TOPK) outrow[mycol] = expf(myval - m) / Z;
}

extern "C" void kernel_launch(void* const* d_in, const int* in_sizes, int n_in,
                              void* d_out, int out_size, void* d_ws, size_t ws_size,
                              hipStream_t stream) {
  const float* x  = (const float*)d_in[0];
  const float* Wq = (const float*)d_in[1];
  const float* bq = (const float*)d_in[2];
  const float* Wk = (const float*)d_in[3];
  const float* bk = (const float*)d_in[4];
  float* out = (float*)d_out;

  const long NE = (long)NB * BN * BD;  // 2,097,152 elements
  double* Qd = (double*)d_ws;                          // 16 MB
  double* Kd = Qd + NE;                                // 16 MB
  unsigned short* Khi = (unsigned short*)(Kd + NE);    // 4 MB
  unsigned short* cand = Khi + NE;                     // 4 MB (NB*BN*CAND)
  unsigned int* cnt = (unsigned int*)(cand + (long)NB * BN * CAND);  // 64 KB

  proj_kernel<<<NB * BN / 32, 256, 0, stream>>>(x, Wq, bq, Wk, bk, Qd, Kd, Khi);
  screen_kernel<<<NB * (BN / 64), 512, 0, stream>>>(Qd, Khi, cand, cnt);
  finalize_kernel<<<NB * (BN / 4), 256, 0, stream>>>(Qd, Kd, cand, cnt, out);
}